// Round 7
// baseline (113.754 us; speedup 1.0000x reference)
//
#include <hip/hip_runtime.h>

// Fully-fused bior3.5 DWT, J=3, zero-padding. NBLK=8 tiles/row, 8 blocks/CU,
// XOR-swizzled LDS, 4 barriers, packed dual-FP32 FMA (R11: v_pk_fma_f32 via
// __builtin_elementwise_fma on float2 ext-vectors, bit-identical).
//
// R12 = R11 (total 113.6us, kernel ~27.6us) + ONE change: per-level K
// rebalance. R11 used K=8 at every level -> P3's L2 compute ran on 67/256
// threads (1.05 waves) and P4's L3 on 33 threads (0.5 waves): one wave
// serially issues 96 pk-FMAs + 7 LDS reads while 3 waves sleep at the
// barrier. New: L1 K=8 (unchanged, 135 thr), L2 K=4 (134 thr, 48 pk/thr),
// L3 K=2 (129 thr, 24 pk/thr). Per-phase serial compute halves/quarters;
// LDS reads +~8 wave-ops/block (window overlap amplification at smaller K).
// Stores stay vector-aligned: L2 writes one float4 per band (f4 idx 275+tid
// lo2, 416+tid hi2); L3 stashes float2 pairs (within-f4-slot, 8B aligned).
// span2 is provably mult-of-4 for all B (c2e=516(B+1) or 4104) -> no L2
// tail; span3 odd only at B=7 -> scalar tail there. Numerics bit-identical.
//
// Kept: R10 write-path (LDS stash -> lane-contiguous nt flush; direct
// interleaved stores amplified WRITE 82-99MB in R8/R9), R6 XCD remap +
// lgkm-only barriers, R5 parity fix via static_asserts, Cfg &~3 rounding.
//
// LDS (13.3 KB/block):
//   xs[2208]: P1-P2 staged x (+halo). P3+: hi1 stash [0,span1),
//             lo2 [1088,1648), hi2 stash [1664,1664+span2).
//   l1[1120]: P2-P3 lo1 coeffs (pad 12). P4+: lo3 [0,span3), hi3 [272,..).

#define FILT_LEN 12
#define ROWS  1024
#define N1    16384
#define O1    8197
#define O2    4104
#define O3    2057
#define NBLK  8
#define T1    1025
#define T2    513
#define T3    258
#define NTHR  256

#define XCAP    2208     // floats (552 float4)
#define L1CAP   1120
#define LO2_OFF 1088     // in xs; region size LO2SZ
#define LO2SZ   560
#define HB2_OFF 1664     // in xs
#define HI3_OFF 272      // in l1

typedef float vf4 __attribute__((ext_vector_type(4)));
typedef float vf2 __attribute__((ext_vector_type(2)));

constexpr int cmin(int a, int b) { return a < b ? a : b; }
constexpr int cmax(int a, int b) { return a > b ? a : b; }

__device__ __forceinline__ int sw4(int f4) { return f4 ^ ((f4 >> 3) & 7); }
__device__ __forceinline__ float4 ld4(const float* p, int f4) {
    return reinterpret_cast<const float4*>(p)[sw4(f4)];
}
__device__ __forceinline__ void st4(float* p, int f4, float4 v) {
    reinterpret_cast<float4*>(p)[sw4(f4)] = v;
}
__device__ __forceinline__ float ldss(const float* p, int j) {
    return p[(sw4(j >> 2) << 2) | (j & 3)];
}
__device__ __forceinline__ void stss(float* p, int j, float v) {
    p[(sw4(j >> 2) << 2) | (j & 3)] = v;
}
// LDS float2 store at even logical index j (pair stays inside one f4 slot).
__device__ __forceinline__ void stp2(float* p, int j, float a, float b) {
    *reinterpret_cast<float2*>(p + ((sw4(j >> 2) << 2) | (j & 3))) =
        make_float2(a, b);
}

// Barrier with LDS-only drain (R6). __syncthreads would add vmcnt(0),
// stalling on output stores nothing re-reads. All inter-phase deps are
// through LDS; global loads are consumed by ds_write data deps beforehand.
__device__ __forceinline__ void bar_lgkm() {
    asm volatile("s_waitcnt lgkmcnt(0)" ::: "memory");
    __builtin_amdgcn_s_barrier();
    asm volatile("" ::: "memory");
}

__device__ __forceinline__ void ntst(float* p, float v) {
    __builtin_nontemporal_store(v, p);
}
__device__ __forceinline__ void ntst2(float* p, float a, float b) {
    vf2 v; v.x = a; v.y = b;
    __builtin_nontemporal_store(v, reinterpret_cast<vf2*>(p));
}
__device__ __forceinline__ void ntst4(float* p, float4 u) {
    vf4 v; v.x = u.x; v.y = u.y; v.z = u.z; v.w = u.w;
    __builtin_nontemporal_store(v, reinterpret_cast<vf4*>(p));
}

// Vectorized contiguous flush: logical stash range [LO,HI) at stash offset
// SOFF (mult of 4) -> g[LO..HI). Body is ld4 + float4 nt stores (lane-
// contiguous, wave = 4KB solid); head/tail (<4 elems each) scalar.
template<int LO, int HI, int SOFF>
__device__ __forceinline__ void flushv(const float* s, float* g, const int tid) {
    static_assert((SOFF & 3) == 0, "stash offset f4-aligned");
    constexpr int A  = (LO + 3) & ~3;
    constexpr int Bq = HI & ~3;
    if (tid < A - LO)
        ntst(g + LO + tid, ldss(s, SOFF + LO + tid));
    if (tid >= 4 && tid < 4 + (HI - Bq))
        ntst(g + Bq + (tid - 4), ldss(s, SOFF + Bq + (tid - 4)));
    for (int i = A + 4 * tid; i < Bq; i += 4 * NTHR)
        ntst4(g + i, ld4(s, (SOFF + i) >> 2));
}

// float2 flush for the level-3 bands (global base only guaranteed even).
template<int HI, int SOFF>
__device__ __forceinline__ void flush2(const float* s, float* g, const int tid) {
    static_assert((SOFF & 3) == 0, "stash offset f4-aligned");
    constexpr int Bq = HI & ~1;
    for (int i = 2 * tid; i < Bq; i += 2 * NTHR) {
        const float* q = s + ((sw4((SOFF + i) >> 2) << 2) | ((SOFF + i) & 3));
        ntst2(g + i, q[0], q[1]);
    }
    if ((HI & 1) && tid == 0) ntst(g + Bq, ldss(s, SOFF + Bq));
}

__device__ __forceinline__ constexpr float h0tap(int i) {
    constexpr float H[FILT_LEN] = {
        -0.013810679320049757f, 0.04143203796014927f, 0.052480581416189075f,
        -0.26792717880896527f, -0.07181553246425873f, 0.966747552403483f,
        0.966747552403483f, -0.07181553246425873f, -0.26792717880896527f,
        0.052480581416189075f, 0.04143203796014927f, -0.013810679320049757f};
    return H[i];
}
__device__ __forceinline__ constexpr float h1tap(int i) {
    return h0tap(FILT_LEN - 1 - i) * ((i & 1) ? 1.0f : -1.0f);
}
__device__ __forceinline__ vf2 tap2(int l) {
    vf2 t; t.x = h0tap(l); t.y = h1tap(l); return t;
}

// Packed (lo,hi) FMA core: acc += (v,v) * (h0[l],h1[l]).
// Bit-identical to the scalar pair; one v_pk_fma_f32 instead of two v_fma.
__device__ __forceinline__ void pkfma(vf2& acc, float v, int l) {
#if __has_builtin(__builtin_elementwise_fma)
    vf2 vv; vv.x = v; vv.y = v;
    acc = __builtin_elementwise_fma(vv, tap2(l), acc);
#else
    acc.x = fmaf(v, h0tap(l), acc.x);
    acc.y = fmaf(v, h1tap(l), acc.y);
#endif
}

template<int B>
struct Cfg {
    static constexpr int s1 = B * T1, e1 = cmin(s1 + T1, O1);
    static constexpr int s2 = B * T2, e2 = cmin(s2 + T2, O2);
    static constexpr int s3 = B * T3, e3 = cmin(s3 + T3, O3);
    // mult-of-4 rounding: keeps parity (R5 fix) and f4-aligns stash math.
    static constexpr int c2s = cmax(0, cmin(s2, 2 * s3 - 10)) & ~3;
    static constexpr int c2e = cmin(O2, cmax(e2, 2 * e3));
    static constexpr int c1s = cmax(0, cmin(s1, 2 * c2s - 10)) & ~3;
    static constexpr int c1e = cmin(O1, cmax(e1, 2 * c2e));
    static constexpr int span1 = c1e - c1s;     // <= ~1080
    static constexpr int span2 = c2e - c2s;     // <= ~536, mult of 4
    static constexpr int span3 = e3 - s3;       // <= 258
    static constexpr int xbase = 2 * c1s - 12;  // mult of 4
    static constexpr int D2 = 2 * c2s - 10 - c1s + 12;   // even, >=0
    static constexpr int ab2 = D2 & ~3, p2 = D2 & 3;     // p2 in {0,2}
    static constexpr int D3 = 2 * s3 - 10 - c2s + 12;    // even, >=0
    static constexpr int ab3 = D3 & ~3, p3 = D3 & 3;     // p3 in {0,2}
    static constexpr int zt1 = L1CAP - (12 + span1);
    static constexpr int zt2 = LO2SZ - (12 + span2);
    static constexpr int o1s = s1 - c1s, o1e = e1 - c1s;  // owned hi1 range
    static constexpr int o2s = s2 - c2s, o2e = e2 - c2s;  // owned hi2 range

    static_assert(D2 >= 0 && D3 >= 0, "pad origin");
    static_assert((D2 & 1) == 0 && (D3 & 1) == 0, "window parity (R5 bug)");
    static_assert(p2 <= 2 && p3 <= 2, "window shift fits window array");
    static_assert((c1s & 3) == 0 && (c2s & 3) == 0, "span starts mult-of-4");
    static_assert((xbase & 3) == 0, "x staging alignment");
    static_assert(zt1 >= 0 && zt1 <= NTHR, "l1 tail zero in one pass");
    static_assert(zt2 >= 0 && zt2 <= NTHR, "lo2 tail zero in one pass");
    static_assert(span1 <= 8 * NTHR, "L1 single K=8 pass");
    static_assert(span2 <= 4 * NTHR, "L2 single K=4 pass");
    static_assert(span3 <= 2 * NTHR, "L3 single K=2 pass");
    static_assert((span2 & 3) == 0, "L2 has no tail (store path)");
    static_assert(2 * (((span1 - 1) / 8) * 8) + 28 <= XCAP, "L1 window read");
    static_assert(2 * (((span2 - 1) / 4) * 4) + ab2 + 20 <= L1CAP, "L2 window read");
    static_assert(2 * (((span3 - 1) / 2) * 2) + ab3 + 16 <= LO2SZ, "L3 window read");
    static_assert(span1 <= LO2_OFF, "hi1 stash fits");
    static_assert(HB2_OFF + span2 <= XCAP, "hi2 stash fits");
    static_assert(HI3_OFF + span3 <= L1CAP, "hi3 stash fits");
    static_assert(HI3_OFF >= span3, "lo3/hi3 disjoint");
    static_assert(o1e <= span1 && o2e <= span2, "owned range inside span");
};

template<int B>
__device__ __forceinline__ void body(
    const float* __restrict__ xrow,
    float* __restrict__ lo3r, float* __restrict__ hi1r,
    float* __restrict__ hi2r, float* __restrict__ hi3r,
    float* __restrict__ xs, float* __restrict__ l1, const int tid)
{
    using C = Cfg<B>;

    // ---------- P1: stage x (swizzled), zero l1 pads ----------
    if constexpr (C::xbase >= 0 && C::xbase + XCAP <= N1) {
        st4(xs, tid,       *reinterpret_cast<const float4*>(xrow + C::xbase + 4 * tid));
        st4(xs, tid + 256, *reinterpret_cast<const float4*>(xrow + C::xbase + 1024 + 4 * tid));
        if (tid < XCAP / 4 - 512)
            st4(xs, tid + 512, *reinterpret_cast<const float4*>(xrow + C::xbase + 2048 + 4 * tid));
    } else {
        for (int i = tid; i < XCAP / 4; i += NTHR) {
            const int g0 = C::xbase + 4 * i;
            float4 v;
            if (g0 >= 0 && g0 + 4 <= N1) {
                v = *reinterpret_cast<const float4*>(xrow + g0);
            } else {
                v.x = ((unsigned)(g0 + 0) < (unsigned)N1) ? xrow[g0 + 0] : 0.f;
                v.y = ((unsigned)(g0 + 1) < (unsigned)N1) ? xrow[g0 + 1] : 0.f;
                v.z = ((unsigned)(g0 + 2) < (unsigned)N1) ? xrow[g0 + 2] : 0.f;
                v.w = ((unsigned)(g0 + 3) < (unsigned)N1) ? xrow[g0 + 3] : 0.f;
            }
            st4(xs, i, v);
        }
    }
    if (tid < 12)      stss(l1, tid, 0.f);
    if (tid < C::zt1)  stss(l1, 12 + C::span1 + tid, 0.f);
    bar_lgkm();

    // ---------- P2: Level 1, K=8: lo1 -> LDS, hi1 -> regs ----------
    float hr1[8];
    const int tt1 = tid * 8;
    if (tt1 < C::span1) {
        float w[28];
#pragma unroll
        for (int m = 0; m < 7; ++m) {
            const float4 v = ld4(xs, tid * 4 + m);   // logical 2*tt1 = 16*tid
            w[4 * m + 0] = v.x; w[4 * m + 1] = v.y;
            w[4 * m + 2] = v.z; w[4 * m + 3] = v.w;
        }
        vf2 ac[8];
#pragma unroll
        for (int k = 0; k < 8; ++k) { ac[k].x = 0.f; ac[k].y = 0.f; }
#pragma unroll
        for (int l = 0; l < FILT_LEN; ++l) {
#pragma unroll
            for (int k = 0; k < 8; ++k)
                pkfma(ac[k], w[2 * k + 2 + l], l);   // x idx 2t-10+l, base 2t-12
        }
#pragma unroll
        for (int k = 0; k < 8; ++k) hr1[k] = ac[k].y;
        if (tt1 + 8 <= C::span1) {                    // lo1 at logical 12+tt1
            st4(l1, 3 + 2 * tid, make_float4(ac[0].x, ac[1].x, ac[2].x, ac[3].x));
            st4(l1, 4 + 2 * tid, make_float4(ac[4].x, ac[5].x, ac[6].x, ac[7].x));
        } else {
#pragma unroll
            for (int k = 0; k < 8; ++k)
                if (tt1 + k < C::span1) stss(l1, 12 + tt1 + k, ac[k].x);
        }
    }
    bar_lgkm();

    // ---------- P3: stash hi1; zero lo2 pads; Level 2, K=4 ----------
    if (tt1 < C::span1) {
        if (tt1 + 8 <= C::span1) {
            st4(xs, 2 * tid,     make_float4(hr1[0], hr1[1], hr1[2], hr1[3]));
            st4(xs, 2 * tid + 1, make_float4(hr1[4], hr1[5], hr1[6], hr1[7]));
        } else {
#pragma unroll
            for (int k = 0; k < 8; ++k)
                if (tt1 + k < C::span1) stss(xs, tt1 + k, hr1[k]);
        }
    }
    if (tid < 12)      stss(xs, LO2_OFF + tid, 0.f);
    if (tid < C::zt2)  stss(xs, LO2_OFF + 12 + C::span2 + tid, 0.f);

    {
        const int tt2 = tid * 4;                     // K=4: ~134 threads
        if (tt2 < C::span2) {
            float w[20];
#pragma unroll
            for (int m = 0; m < 5; ++m) {   // l1 logical 2*tt2+ab2 = 8*tid+ab2
                const float4 v = ld4(l1, tid * 2 + (C::ab2 >> 2) + m);
                w[4 * m + 0] = v.x; w[4 * m + 1] = v.y;
                w[4 * m + 2] = v.z; w[4 * m + 3] = v.w;
            }
            vf2 ac[4];
#pragma unroll
            for (int k = 0; k < 4; ++k) { ac[k].x = 0.f; ac[k].y = 0.f; }
#pragma unroll
            for (int l = 0; l < FILT_LEN; ++l) {
#pragma unroll
                for (int k = 0; k < 4; ++k)
                    pkfma(ac[k], w[2 * k + l + C::p2], l);
            }
            // span2 is mult-of-4 (assert) -> always full vector store
            // lo2 at logical LO2_OFF+12+tt2 = 1100+4*tid -> f4 = 275 + tid
            st4(xs, 275 + tid, make_float4(ac[0].x, ac[1].x, ac[2].x, ac[3].x));
            // hi2 stash at HB2_OFF+tt2 = 1664+4*tid -> f4 = 416 + tid
            st4(xs, 416 + tid, make_float4(ac[0].y, ac[1].y, ac[2].y, ac[3].y));
        }
    }
    bar_lgkm();

    // ---------- P4: flush hi1+hi2 (vectorized); Level 3, K=2 -> stash in l1 ----------
    flushv<C::o1s, C::o1e, 0>(xs, hi1r + C::c1s, tid);
    flushv<C::o2s, C::o2e, HB2_OFF>(xs, hi2r + C::c2s, tid);

    {
        const int tt3 = tid * 2;                     // K=2: ~129 threads
        if (tt3 < C::span3) {
            float w[16];
#pragma unroll
            for (int m = 0; m < 4; ++m) {   // xs logical LO2_OFF+2*tt3+ab3 = LO2_OFF+4*tid+ab3
                const float4 v = ld4(xs, (LO2_OFF >> 2) + tid + (C::ab3 >> 2) + m);
                w[4 * m + 0] = v.x; w[4 * m + 1] = v.y;
                w[4 * m + 2] = v.z; w[4 * m + 3] = v.w;
            }
            vf2 ac[2];
#pragma unroll
            for (int k = 0; k < 2; ++k) { ac[k].x = 0.f; ac[k].y = 0.f; }
#pragma unroll
            for (int l = 0; l < FILT_LEN; ++l) {
#pragma unroll
                for (int k = 0; k < 2; ++k)
                    pkfma(ac[k], w[2 * k + l + C::p3], l);
            }
            if (tt3 + 2 <= C::span3) {
                stp2(l1, tt3,           ac[0].x, ac[1].x);   // lo3 stash
                stp2(l1, HI3_OFF + tt3, ac[0].y, ac[1].y);   // hi3 stash
            } else {                                          // odd span3 (B=7)
                stss(l1, tt3, ac[0].x);
                stss(l1, HI3_OFF + tt3, ac[0].y);
            }
        }
    }
    bar_lgkm();   // lgkm-only: the hi1/hi2 global stores above need NO drain

    // ---------- P5: flush lo3, hi3 (float2 vectorized) ----------
    flush2<C::span3, 0>(l1, lo3r + C::s3, tid);
    flush2<C::span3, HI3_OFF>(l1, hi3r + C::s3, tid);
}

__global__ __launch_bounds__(NTHR, 8) void dwt_fused_kernel(
    const float* __restrict__ x,
    float* __restrict__ lo3, float* __restrict__ hi1,
    float* __restrict__ hi2, float* __restrict__ hi3)
{
    __shared__ __align__(16) float xs[XCAP];
    __shared__ __align__(16) float l1[L1CAP];

    // XCD-aware remap (R6): all 8 tiles of a row land on one XCD,
    // dispatch-adjacent, so inter-tile staging halos are L2 hits.
    const int tile = blockIdx.y & 7;
    const int row  = (int)blockIdx.x * 128 + ((int)blockIdx.y >> 3);
    const int tid = threadIdx.x;
    const float* xrow = x + (size_t)row * N1;
    float* lo3r = lo3 + (size_t)row * O3;
    float* hi1r = hi1 + (size_t)row * O1;
    float* hi2r = hi2 + (size_t)row * O2;
    float* hi3r = hi3 + (size_t)row * O3;

    switch (tile) {
        case 0:  body<0>(xrow, lo3r, hi1r, hi2r, hi3r, xs, l1, tid); break;
        case 1:  body<1>(xrow, lo3r, hi1r, hi2r, hi3r, xs, l1, tid); break;
        case 2:  body<2>(xrow, lo3r, hi1r, hi2r, hi3r, xs, l1, tid); break;
        case 3:  body<3>(xrow, lo3r, hi1r, hi2r, hi3r, xs, l1, tid); break;
        case 4:  body<4>(xrow, lo3r, hi1r, hi2r, hi3r, xs, l1, tid); break;
        case 5:  body<5>(xrow, lo3r, hi1r, hi2r, hi3r, xs, l1, tid); break;
        case 6:  body<6>(xrow, lo3r, hi1r, hi2r, hi3r, xs, l1, tid); break;
        default: body<7>(xrow, lo3r, hi1r, hi2r, hi3r, xs, l1, tid); break;
    }
}

extern "C" void kernel_launch(void* const* d_in, const int* in_sizes, int n_in,
                              void* d_out, int out_size, void* d_ws, size_t ws_size,
                              hipStream_t stream)
{
    const float* x = (const float*)d_in[0];
    float* out = (float*)d_out;

    // Output layout: (lo3, hi1, hi2, hi3) concatenated flat
    float* lo3 = out;
    float* hi1 = out + (size_t)ROWS * O3;
    float* hi2 = hi1 + (size_t)ROWS * O1;
    float* hi3 = hi2 + (size_t)ROWS * O2;

    dwt_fused_kernel<<<dim3(NBLK, ROWS), dim3(NTHR), 0, stream>>>(
        x, lo3, hi1, hi2, hi3);
}

// Round 8
// 113.428 us; speedup vs baseline: 1.0029x; 1.0029x over previous
//
#include <hip/hip_runtime.h>

// Fully-fused bior3.5 DWT, J=3, zero-padding. NBLK=8 tiles/row, 8 blocks/CU,
// XOR-swizzled LDS, packed dual-FP32 FMA, 3 barriers.
//
// R13 = R12 (113.75us; kernel ~27.9us vs 16.7us HBM floor) + ONE structural
// change: L1 reads x DIRECTLY from global, x staging deleted. The P1 stage +
// P2 LDS window reads were ~35% of LDS-pipe wave-ops and exist only to share
// halos between ADJACENT threads -- L1/L2 cache does that for free: thread t
// loads [xbase+16t, +28) as 7 float4 (lanes stride 64B; each line fetched
// once, re-hit from L1 for the overlapping taps). Interior tiles B=1..6 are
// compile-time-provably in-bounds (xbase>=0 && 2*c1e<=N1); B=0/7 take
// per-float4 guards (same logic as the old staging edge path). With xs free
// from the start, hi1 stashes in the SAME phase as L1 compute, and lo2-pad
// zeroing merges up -> 4 phases, 3 barriers:
//   A: zero pads; L1 direct-global -> lo1->l1, hi1->xs stash | bar
//   B: flush hi1; L2 (K=4) -> lo2->xs, hi2->xs stash         | bar
//   C: flush hi2; L3 (K=2) -> lo3/hi3 -> l1 stash            | bar
//   D: flush lo3, hi3.
// FMA chain untouched -> bit-identical (absmax must stay 0.0).
//
// Evidence trail kept: R10 write-path (LDS stash -> lane-contiguous nt
// flush; direct interleaved stores amplified WRITE 82-99MB in R8/R9).
// R11 pk-FMA (-6.5us, VALU halved). R12 K-rebalance (neutral; kept).
// R6 XCD remap + lgkm-only barriers. R5 parity fix via static_asserts.
//
// LDS (13.3 KB/block):
//   xs[2208]: hi1 stash [0,span1), lo2 [1088,1648), hi2 stash [1664,..).
//   l1[1120]: A-B lo1 coeffs (pad 12). C+: lo3 [0,span3), hi3 [272,..).

#define FILT_LEN 12
#define ROWS  1024
#define N1    16384
#define O1    8197
#define O2    4104
#define O3    2057
#define NBLK  8
#define T1    1025
#define T2    513
#define T3    258
#define NTHR  256

#define XCAP    2208     // floats (552 float4)
#define L1CAP   1120
#define LO2_OFF 1088     // in xs; region size LO2SZ
#define LO2SZ   560
#define HB2_OFF 1664     // in xs
#define HI3_OFF 272      // in l1

typedef float vf4 __attribute__((ext_vector_type(4)));
typedef float vf2 __attribute__((ext_vector_type(2)));

constexpr int cmin(int a, int b) { return a < b ? a : b; }
constexpr int cmax(int a, int b) { return a > b ? a : b; }

__device__ __forceinline__ int sw4(int f4) { return f4 ^ ((f4 >> 3) & 7); }
__device__ __forceinline__ float4 ld4(const float* p, int f4) {
    return reinterpret_cast<const float4*>(p)[sw4(f4)];
}
__device__ __forceinline__ void st4(float* p, int f4, float4 v) {
    reinterpret_cast<float4*>(p)[sw4(f4)] = v;
}
__device__ __forceinline__ float ldss(const float* p, int j) {
    return p[(sw4(j >> 2) << 2) | (j & 3)];
}
__device__ __forceinline__ void stss(float* p, int j, float v) {
    p[(sw4(j >> 2) << 2) | (j & 3)] = v;
}
// LDS float2 store at even logical index j (pair stays inside one f4 slot).
__device__ __forceinline__ void stp2(float* p, int j, float a, float b) {
    *reinterpret_cast<float2*>(p + ((sw4(j >> 2) << 2) | (j & 3))) =
        make_float2(a, b);
}

// Barrier with LDS-only drain (R6). __syncthreads would add vmcnt(0),
// stalling on output stores nothing re-reads. All inter-phase deps are
// through LDS; global loads are consumed by data deps beforehand (compiler
// inserts the needed vmcnt).
__device__ __forceinline__ void bar_lgkm() {
    asm volatile("s_waitcnt lgkmcnt(0)" ::: "memory");
    __builtin_amdgcn_s_barrier();
    asm volatile("" ::: "memory");
}

__device__ __forceinline__ void ntst(float* p, float v) {
    __builtin_nontemporal_store(v, p);
}
__device__ __forceinline__ void ntst2(float* p, float a, float b) {
    vf2 v; v.x = a; v.y = b;
    __builtin_nontemporal_store(v, reinterpret_cast<vf2*>(p));
}
__device__ __forceinline__ void ntst4(float* p, float4 u) {
    vf4 v; v.x = u.x; v.y = u.y; v.z = u.z; v.w = u.w;
    __builtin_nontemporal_store(v, reinterpret_cast<vf4*>(p));
}

// Vectorized contiguous flush: logical stash range [LO,HI) at stash offset
// SOFF (mult of 4) -> g[LO..HI). Body is ld4 + float4 nt stores (lane-
// contiguous, wave = 4KB solid); head/tail (<4 elems each) scalar.
template<int LO, int HI, int SOFF>
__device__ __forceinline__ void flushv(const float* s, float* g, const int tid) {
    static_assert((SOFF & 3) == 0, "stash offset f4-aligned");
    constexpr int A  = (LO + 3) & ~3;
    constexpr int Bq = HI & ~3;
    if (tid < A - LO)
        ntst(g + LO + tid, ldss(s, SOFF + LO + tid));
    if (tid >= 4 && tid < 4 + (HI - Bq))
        ntst(g + Bq + (tid - 4), ldss(s, SOFF + Bq + (tid - 4)));
    for (int i = A + 4 * tid; i < Bq; i += 4 * NTHR)
        ntst4(g + i, ld4(s, (SOFF + i) >> 2));
}

// float2 flush for the level-3 bands (global base only guaranteed even).
template<int HI, int SOFF>
__device__ __forceinline__ void flush2(const float* s, float* g, const int tid) {
    static_assert((SOFF & 3) == 0, "stash offset f4-aligned");
    constexpr int Bq = HI & ~1;
    for (int i = 2 * tid; i < Bq; i += 2 * NTHR) {
        const float* q = s + ((sw4((SOFF + i) >> 2) << 2) | ((SOFF + i) & 3));
        ntst2(g + i, q[0], q[1]);
    }
    if ((HI & 1) && tid == 0) ntst(g + Bq, ldss(s, SOFF + Bq));
}

__device__ __forceinline__ constexpr float h0tap(int i) {
    constexpr float H[FILT_LEN] = {
        -0.013810679320049757f, 0.04143203796014927f, 0.052480581416189075f,
        -0.26792717880896527f, -0.07181553246425873f, 0.966747552403483f,
        0.966747552403483f, -0.07181553246425873f, -0.26792717880896527f,
        0.052480581416189075f, 0.04143203796014927f, -0.013810679320049757f};
    return H[i];
}
__device__ __forceinline__ constexpr float h1tap(int i) {
    return h0tap(FILT_LEN - 1 - i) * ((i & 1) ? 1.0f : -1.0f);
}
__device__ __forceinline__ vf2 tap2(int l) {
    vf2 t; t.x = h0tap(l); t.y = h1tap(l); return t;
}

// Packed (lo,hi) FMA core: acc += (v,v) * (h0[l],h1[l]).
// Bit-identical to the scalar pair; one v_pk_fma_f32 instead of two v_fma.
__device__ __forceinline__ void pkfma(vf2& acc, float v, int l) {
#if __has_builtin(__builtin_elementwise_fma)
    vf2 vv; vv.x = v; vv.y = v;
    acc = __builtin_elementwise_fma(vv, tap2(l), acc);
#else
    acc.x = fmaf(v, h0tap(l), acc.x);
    acc.y = fmaf(v, h1tap(l), acc.y);
#endif
}

template<int B>
struct Cfg {
    static constexpr int s1 = B * T1, e1 = cmin(s1 + T1, O1);
    static constexpr int s2 = B * T2, e2 = cmin(s2 + T2, O2);
    static constexpr int s3 = B * T3, e3 = cmin(s3 + T3, O3);
    // mult-of-4 rounding: keeps parity (R5 fix) and f4-aligns stash math.
    static constexpr int c2s = cmax(0, cmin(s2, 2 * s3 - 10)) & ~3;
    static constexpr int c2e = cmin(O2, cmax(e2, 2 * e3));
    static constexpr int c1s = cmax(0, cmin(s1, 2 * c2s - 10)) & ~3;
    static constexpr int c1e = cmin(O1, cmax(e1, 2 * c2e));
    static constexpr int span1 = c1e - c1s;     // <= ~1080
    static constexpr int span2 = c2e - c2s;     // <= ~536, mult of 4
    static constexpr int span3 = e3 - s3;       // <= 258
    static constexpr int xbase = 2 * c1s - 12;  // mult of 4
    static constexpr int D2 = 2 * c2s - 10 - c1s + 12;   // even, >=0
    static constexpr int ab2 = D2 & ~3, p2 = D2 & 3;     // p2 in {0,2}
    static constexpr int D3 = 2 * s3 - 10 - c2s + 12;    // even, >=0
    static constexpr int ab3 = D3 & ~3, p3 = D3 & 3;     // p3 in {0,2}
    static constexpr int zt1 = L1CAP - (12 + span1);
    static constexpr int zt2 = LO2SZ - (12 + span2);
    static constexpr int o1s = s1 - c1s, o1e = e1 - c1s;  // owned hi1 range
    static constexpr int o2s = s2 - c2s, o2e = e2 - c2s;  // owned hi2 range
    // Direct-global L1 window: thread t reads [xbase+16t, xbase+16t+28);
    // max end over live threads == 2*c1e. Interior <=> provably in-bounds.
    static constexpr bool interior = (xbase >= 0) && (2 * c1e <= N1);

    static_assert(D2 >= 0 && D3 >= 0, "pad origin");
    static_assert((D2 & 1) == 0 && (D3 & 1) == 0, "window parity (R5 bug)");
    static_assert(p2 <= 2 && p3 <= 2, "window shift fits window array");
    static_assert((c1s & 3) == 0 && (c2s & 3) == 0, "span starts mult-of-4");
    static_assert((xbase & 3) == 0, "x load alignment");
    static_assert(zt1 >= 0 && zt1 <= NTHR, "l1 tail zero in one pass");
    static_assert(zt2 >= 0 && zt2 <= NTHR, "lo2 tail zero in one pass");
    static_assert(span1 <= 8 * NTHR, "L1 single K=8 pass");
    static_assert(span2 <= 4 * NTHR, "L2 single K=4 pass");
    static_assert(span3 <= 2 * NTHR, "L3 single K=2 pass");
    static_assert((span2 & 3) == 0, "L2 has no tail (store path)");
    static_assert(2 * (((span2 - 1) / 4) * 4) + ab2 + 20 <= L1CAP, "L2 window read");
    static_assert(2 * (((span3 - 1) / 2) * 2) + ab3 + 16 <= LO2SZ, "L3 window read");
    static_assert(span1 <= LO2_OFF, "hi1 stash fits");
    static_assert(HB2_OFF + span2 <= XCAP, "hi2 stash fits");
    static_assert(HI3_OFF + span3 <= L1CAP, "hi3 stash fits");
    static_assert(HI3_OFF >= span3, "lo3/hi3 disjoint");
    static_assert(o1e <= span1 && o2e <= span2, "owned range inside span");
};

template<int B>
__device__ __forceinline__ void body(
    const float* __restrict__ xrow,
    float* __restrict__ lo3r, float* __restrict__ hi1r,
    float* __restrict__ hi2r, float* __restrict__ hi3r,
    float* __restrict__ xs, float* __restrict__ l1, const int tid)
{
    using C = Cfg<B>;

    // ---------- A: zero pads; L1 direct-from-global; lo1->l1, hi1->xs ----------
    // Pad zeroing targets (l1[0,12), l1 tail, xs LO2 pads) are disjoint from
    // every same-phase data write (lo1 at l1[12,12+span1), hi1 at xs[0,span1)
    // with span1 <= LO2_OFF) -> no intra-phase barrier needed.
    if (tid < 12)      stss(l1, tid, 0.f);
    if (tid < C::zt1)  stss(l1, 12 + C::span1 + tid, 0.f);
    if (tid < 12)      stss(xs, LO2_OFF + tid, 0.f);
    if (tid < C::zt2)  stss(xs, LO2_OFF + 12 + C::span2 + tid, 0.f);

    {
        const int tt1 = tid * 8;
        if (tt1 < C::span1) {
            float w[28];
            if constexpr (C::interior) {            // B=1..6: provably in-bounds
                const float* wp = xrow + C::xbase + 16 * tid;
#pragma unroll
                for (int m = 0; m < 7; ++m) {
                    const float4 v = *reinterpret_cast<const float4*>(wp + 4 * m);
                    w[4 * m + 0] = v.x; w[4 * m + 1] = v.y;
                    w[4 * m + 2] = v.z; w[4 * m + 3] = v.w;
                }
            } else {                                 // B=0 / B=7: guarded
#pragma unroll
                for (int m = 0; m < 7; ++m) {
                    const int g0 = C::xbase + 16 * tid + 4 * m;
                    float4 v;
                    if (g0 >= 0 && g0 + 4 <= N1) {
                        v = *reinterpret_cast<const float4*>(xrow + g0);
                    } else {
                        v.x = ((unsigned)(g0 + 0) < (unsigned)N1) ? xrow[g0 + 0] : 0.f;
                        v.y = ((unsigned)(g0 + 1) < (unsigned)N1) ? xrow[g0 + 1] : 0.f;
                        v.z = ((unsigned)(g0 + 2) < (unsigned)N1) ? xrow[g0 + 2] : 0.f;
                        v.w = ((unsigned)(g0 + 3) < (unsigned)N1) ? xrow[g0 + 3] : 0.f;
                    }
                    w[4 * m + 0] = v.x; w[4 * m + 1] = v.y;
                    w[4 * m + 2] = v.z; w[4 * m + 3] = v.w;
                }
            }
            vf2 ac[8];
#pragma unroll
            for (int k = 0; k < 8; ++k) { ac[k].x = 0.f; ac[k].y = 0.f; }
#pragma unroll
            for (int l = 0; l < FILT_LEN; ++l) {
#pragma unroll
                for (int k = 0; k < 8; ++k)
                    pkfma(ac[k], w[2 * k + 2 + l], l);  // x idx 2t-10+l, base 2t-12
            }
            if (tt1 + 8 <= C::span1) {
                // lo1 at logical 12+tt1 -> f4 3+2*tid, 4+2*tid
                st4(l1, 3 + 2 * tid, make_float4(ac[0].x, ac[1].x, ac[2].x, ac[3].x));
                st4(l1, 4 + 2 * tid, make_float4(ac[4].x, ac[5].x, ac[6].x, ac[7].x));
                // hi1 stash at logical tt1 -> f4 2*tid, 2*tid+1
                st4(xs, 2 * tid,     make_float4(ac[0].y, ac[1].y, ac[2].y, ac[3].y));
                st4(xs, 2 * tid + 1, make_float4(ac[4].y, ac[5].y, ac[6].y, ac[7].y));
            } else {
#pragma unroll
                for (int k = 0; k < 8; ++k) {
                    if (tt1 + k < C::span1) {
                        stss(l1, 12 + tt1 + k, ac[k].x);
                        stss(xs, tt1 + k, ac[k].y);
                    }
                }
            }
        }
    }
    bar_lgkm();

    // ---------- B: flush hi1; Level 2, K=4 ----------
    flushv<C::o1s, C::o1e, 0>(xs, hi1r + C::c1s, tid);
    {
        const int tt2 = tid * 4;                     // ~134 threads
        if (tt2 < C::span2) {
            float w[20];
#pragma unroll
            for (int m = 0; m < 5; ++m) {   // l1 logical 2*tt2+ab2 = 8*tid+ab2
                const float4 v = ld4(l1, tid * 2 + (C::ab2 >> 2) + m);
                w[4 * m + 0] = v.x; w[4 * m + 1] = v.y;
                w[4 * m + 2] = v.z; w[4 * m + 3] = v.w;
            }
            vf2 ac[4];
#pragma unroll
            for (int k = 0; k < 4; ++k) { ac[k].x = 0.f; ac[k].y = 0.f; }
#pragma unroll
            for (int l = 0; l < FILT_LEN; ++l) {
#pragma unroll
                for (int k = 0; k < 4; ++k)
                    pkfma(ac[k], w[2 * k + l + C::p2], l);
            }
            // span2 mult-of-4 (assert) -> always full vector store
            st4(xs, 275 + tid, make_float4(ac[0].x, ac[1].x, ac[2].x, ac[3].x));
            st4(xs, 416 + tid, make_float4(ac[0].y, ac[1].y, ac[2].y, ac[3].y));
        }
    }
    bar_lgkm();

    // ---------- C: flush hi2; Level 3, K=2 -> stash in l1 ----------
    flushv<C::o2s, C::o2e, HB2_OFF>(xs, hi2r + C::c2s, tid);
    {
        const int tt3 = tid * 2;                     // ~129 threads
        if (tt3 < C::span3) {
            float w[16];
#pragma unroll
            for (int m = 0; m < 4; ++m) {   // xs logical LO2_OFF+4*tid+ab3
                const float4 v = ld4(xs, (LO2_OFF >> 2) + tid + (C::ab3 >> 2) + m);
                w[4 * m + 0] = v.x; w[4 * m + 1] = v.y;
                w[4 * m + 2] = v.z; w[4 * m + 3] = v.w;
            }
            vf2 ac[2];
#pragma unroll
            for (int k = 0; k < 2; ++k) { ac[k].x = 0.f; ac[k].y = 0.f; }
#pragma unroll
            for (int l = 0; l < FILT_LEN; ++l) {
#pragma unroll
                for (int k = 0; k < 2; ++k)
                    pkfma(ac[k], w[2 * k + l + C::p3], l);
            }
            if (tt3 + 2 <= C::span3) {
                stp2(l1, tt3,           ac[0].x, ac[1].x);   // lo3 stash
                stp2(l1, HI3_OFF + tt3, ac[0].y, ac[1].y);   // hi3 stash
            } else {                                          // odd span3 (B=7)
                stss(l1, tt3, ac[0].x);
                stss(l1, HI3_OFF + tt3, ac[0].y);
            }
        }
    }
    bar_lgkm();   // lgkm-only: the hi1/hi2 global stores need NO drain here

    // ---------- D: flush lo3, hi3 (float2 vectorized) ----------
    flush2<C::span3, 0>(l1, lo3r + C::s3, tid);
    flush2<C::span3, HI3_OFF>(l1, hi3r + C::s3, tid);
}

__global__ __launch_bounds__(NTHR, 8) void dwt_fused_kernel(
    const float* __restrict__ x,
    float* __restrict__ lo3, float* __restrict__ hi1,
    float* __restrict__ hi2, float* __restrict__ hi3)
{
    __shared__ __align__(16) float xs[XCAP];
    __shared__ __align__(16) float l1[L1CAP];

    // XCD-aware remap (R6): all 8 tiles of a row land on one XCD,
    // dispatch-adjacent, so inter-tile halo re-reads are L2 hits.
    const int tile = blockIdx.y & 7;
    const int row  = (int)blockIdx.x * 128 + ((int)blockIdx.y >> 3);
    const int tid = threadIdx.x;
    const float* xrow = x + (size_t)row * N1;
    float* lo3r = lo3 + (size_t)row * O3;
    float* hi1r = hi1 + (size_t)row * O1;
    float* hi2r = hi2 + (size_t)row * O2;
    float* hi3r = hi3 + (size_t)row * O3;

    switch (tile) {
        case 0:  body<0>(xrow, lo3r, hi1r, hi2r, hi3r, xs, l1, tid); break;
        case 1:  body<1>(xrow, lo3r, hi1r, hi2r, hi3r, xs, l1, tid); break;
        case 2:  body<2>(xrow, lo3r, hi1r, hi2r, hi3r, xs, l1, tid); break;
        case 3:  body<3>(xrow, lo3r, hi1r, hi2r, hi3r, xs, l1, tid); break;
        case 4:  body<4>(xrow, lo3r, hi1r, hi2r, hi3r, xs, l1, tid); break;
        case 5:  body<5>(xrow, lo3r, hi1r, hi2r, hi3r, xs, l1, tid); break;
        case 6:  body<6>(xrow, lo3r, hi1r, hi2r, hi3r, xs, l1, tid); break;
        default: body<7>(xrow, lo3r, hi1r, hi2r, hi3r, xs, l1, tid); break;
    }
}

extern "C" void kernel_launch(void* const* d_in, const int* in_sizes, int n_in,
                              void* d_out, int out_size, void* d_ws, size_t ws_size,
                              hipStream_t stream)
{
    const float* x = (const float*)d_in[0];
    float* out = (float*)d_out;

    // Output layout: (lo3, hi1, hi2, hi3) concatenated flat
    float* lo3 = out;
    float* hi1 = out + (size_t)ROWS * O3;
    float* hi2 = hi1 + (size_t)ROWS * O1;
    float* hi3 = hi2 + (size_t)ROWS * O2;

    dwt_fused_kernel<<<dim3(NBLK, ROWS), dim3(NTHR), 0, stream>>>(
        x, lo3, hi1, hi2, hi3);
}